// Round 10
// baseline (835.954 us; speedup 1.0000x reference)
//
#include <hip/hip_runtime.h>

#define NROW 6
#define NCOL 6
#define BATCH 1024
#define NSITE 36

// LDS bank-conflict swizzle: XOR dword-addr bits [4:2] with bits [7:5].
// Preserves bits [1:0]; constant within any aligned 4-dword window, so
// float4/float2 accesses stay contiguous/aligned; SWZ(0)==0.
__device__ __forceinline__ int SWZ(int a) { return a ^ (((a >> 5) & 7) << 2); }

// Pre-transpose T[site][spin][u=x][r=gp][d=z][l=g] into
// Tm[(site*2+spin)*256 + (gp*4+z)*16 + (g*4+x)]  (73,728 B in d_ws) so the
// main kernel's M rows are contiguous float4s at wave-uniform addresses.
__global__ void peps_reorder_kernel(const float* __restrict__ T,
                                    float* __restrict__ Tm)
{
    int idx = blockIdx.x * 256 + threadIdx.x;   // [0, 18432)
    if (idx >= NSITE * 2 * 256) return;
    int i  = idx & 15;          // i = g*4 + x
    int o  = (idx >> 4) & 15;   // o = gp*4 + z
    int sp = (idx >> 8) & 1;
    int st = idx >> 9;
    int g = i >> 2, x = i & 3, gp = o >> 2, z = o & 3;
    Tm[idx] = T[st * 512 + sp * 256 + x * 64 + gp * 16 + z * 4 + g];
}

// Fixed-slot in-place contraction (R8/R9's verified algebra): state index =
// g*4096 + sum_j slot_j*4^j; step (row,c) reads up-bond x from slot c and
// writes down-bond z back into slot c. ONE barrier/step. State in LDS (64 KB,
// swizzled).
// R9 post-mortem: the binder was 64 *vector* global_load_dwordx4 of M per
// thread-step (wave-uniform addresses!) = 512 KB/block-step of L1 traffic.
// Fix here: all 36 steps fully unrolled and M loads hoisted into UNIFORM
// control flow (outside if(act0)) with literal offsets -> LLVM scalarizes to
// s_load_dwordx4 (1 fetch/wave, SMEM pipe). Only FMAs + LDS ops stay masked.
__global__ __launch_bounds__(512, 4)
void peps_amp_kernel(const int* __restrict__ X, const float* __restrict__ Tm,
                     float* __restrict__ out)
{
    __shared__ float W[16384];   // 65536 B exactly (4^7 fixed-slot state)

    const int b = blockIdx.x;
    const int t = threadIdx.x;
    const int* xrow = X + b * NSITE;

    // PHYS=2: pack the 36 spins into one scalar 64-bit mask (SGPR-resident
    // so every Tm address below is provably wave-uniform).
    unsigned long long sm = 0ull;
    const int4* xp = (const int4*)xrow;
    #pragma unroll
    for (int k = 0; k < 9; ++k) {
        int4 v = xp[k];
        sm |= ((unsigned long long)(v.x & 1)) << (4 * k + 0);
        sm |= ((unsigned long long)(v.y & 1)) << (4 * k + 1);
        sm |= ((unsigned long long)(v.z & 1)) << (4 * k + 2);
        sm |= ((unsigned long long)(v.w & 1)) << (4 * k + 3);
    }
    {
        unsigned lo = __builtin_amdgcn_readfirstlane((int)(sm & 0xffffffffull));
        unsigned hi = __builtin_amdgcn_readfirstlane((int)(sm >> 32));
        sm = ((unsigned long long)hi << 32) | lo;
    }

    if (t == 0) W[0] = 1.0f;     // seed (SWZ(0)==0); covered by step-0 barrier

    const int u0 = 2 * t;        // this thread's two spectators: u0, u0+1

    #pragma unroll
    for (int row = 0; row < NROW; ++row) {
        const int xs = (row == 0) ? 1 : 4;          // up-bond size
        const int zs = (row == NROW - 1) ? 1 : 4;   // down-bond size
        #pragma unroll
        for (int c = 0; c < NCOL; ++c) {
            const int step = row * NCOL + c;        // compile-time
            const int gin  = (c == 0) ? 1 : 4;
            const int gout = (c == NCOL - 1) ? 1 : 4;
            const int lowb  = (zs == 4) ? 2 * c : 0;
            const int highb = (xs == 4) ? 2 * (5 - c) : 0;
            const int scount = 1 << (lowb + highb); // compile-time
            const int p4c = 1 << (2 * c);
            const int lowmask = (1 << lowb) - 1;
            const int mr0 = ((u0 >> lowb) << (2 * c + 2)) | (u0 & lowmask);
            const int mr1 = (((u0 + 1) >> lowb) << (2 * c + 2)) | ((u0 + 1) & lowmask);
            const bool act0 = (u0 < scount);
            const bool act1 = (u0 + 1 < scount);

            // uniform scalar: spin bit + M base for this step
            const int spin = (int)((sm >> step) & 1ull);
            const float4* Ms4 =
                (const float4*)(Tm + (size_t)(step * 2 + spin) * 256);

            __syncthreads();     // the ONLY barrier per step

            // ---- read phase (divergent, thread-private addresses) ----
            float in[16][2];
            if (act0) {
                if (c == 0) {
                    #pragma unroll
                    for (int g = 0; g < 4; ++g) if (g < gin) {
                        float4 r0 = *(const float4*)&W[SWZ(g * 4096 + 4 * u0)];
                        in[g*4+0][0]=r0.x; in[g*4+1][0]=r0.y;
                        in[g*4+2][0]=r0.z; in[g*4+3][0]=r0.w;
                        if (act1) {
                            float4 r1 = *(const float4*)&W[SWZ(g * 4096 + 4 * u0 + 4)];
                            in[g*4+0][1]=r1.x; in[g*4+1][1]=r1.y;
                            in[g*4+2][1]=r1.z; in[g*4+3][1]=r1.w;
                        } else {
                            in[g*4+0][1]=0.f; in[g*4+1][1]=0.f;
                            in[g*4+2][1]=0.f; in[g*4+3][1]=0.f;
                        }
                    }
                } else if (zs == 4) {
                    #pragma unroll
                    for (int g = 0; g < 4; ++g) if (g < gin) {
                        #pragma unroll
                        for (int x = 0; x < 4; ++x) if (x < xs) {
                            float2 r = *(const float2*)&W[SWZ(g * 4096 + x * p4c + mr0)];
                            in[g*4+x][0] = r.x; in[g*4+x][1] = r.y;
                        }
                    }
                } else {
                    #pragma unroll
                    for (int g = 0; g < 4; ++g) if (g < gin) {
                        #pragma unroll
                        for (int x = 0; x < 4; ++x) if (x < xs) {
                            in[g*4+x][0] = W[SWZ(g * 4096 + x * p4c + mr0)];
                            in[g*4+x][1] = act1 ? W[SWZ(g * 4096 + x * p4c + mr1)] : 0.f;
                        }
                    }
                }
            }

            // ---- compute + write; M loads in UNIFORM control flow ----
            #pragma unroll
            for (int gp = 0; gp < 4; ++gp) if (gp < gout) {
                float a[4][2];
                #pragma unroll
                for (int z = 0; z < 4; ++z) if (z < zs) {
                    // uniform loads (s_load): literal offsets off SGPR base
                    float4 mq0 = Ms4[(gp * 4 + z) * 4 + 0];
                    float4 mq1, mq2, mq3;
                    if (gin == 4) {
                        mq1 = Ms4[(gp * 4 + z) * 4 + 1];
                        mq2 = Ms4[(gp * 4 + z) * 4 + 2];
                        mq3 = Ms4[(gp * 4 + z) * 4 + 3];
                    }
                    float s0 = 0.f, s1 = 0.f;
                    if (act0) {
                        s0 += mq0.x * in[0][0]; s1 += mq0.x * in[0][1];
                        if (xs == 4) {
                            s0 += mq0.y * in[1][0]; s1 += mq0.y * in[1][1];
                            s0 += mq0.z * in[2][0]; s1 += mq0.z * in[2][1];
                            s0 += mq0.w * in[3][0]; s1 += mq0.w * in[3][1];
                        }
                        if (gin == 4) {
                            s0 += mq1.x * in[4][0];  s1 += mq1.x * in[4][1];
                            s0 += mq2.x * in[8][0];  s1 += mq2.x * in[8][1];
                            s0 += mq3.x * in[12][0]; s1 += mq3.x * in[12][1];
                            if (xs == 4) {
                                s0 += mq1.y * in[5][0];  s1 += mq1.y * in[5][1];
                                s0 += mq1.z * in[6][0];  s1 += mq1.z * in[6][1];
                                s0 += mq1.w * in[7][0];  s1 += mq1.w * in[7][1];
                                s0 += mq2.y * in[9][0];  s1 += mq2.y * in[9][1];
                                s0 += mq2.z * in[10][0]; s1 += mq2.z * in[10][1];
                                s0 += mq2.w * in[11][0]; s1 += mq2.w * in[11][1];
                                s0 += mq3.y * in[13][0]; s1 += mq3.y * in[13][1];
                                s0 += mq3.z * in[14][0]; s1 += mq3.z * in[14][1];
                                s0 += mq3.w * in[15][0]; s1 += mq3.w * in[15][1];
                            }
                        }
                    }
                    a[z][0] = s0; a[z][1] = s1;
                    if (act0) {
                        if (c != 0 && zs == 4) {
                            *(float2*)&W[SWZ(gp * 4096 + z * p4c + mr0)] =
                                make_float2(s0, s1);
                        } else if (zs == 1) {
                            W[SWZ(gp * 4096 + mr0)] = s0;
                            if (act1) W[SWZ(gp * 4096 + mr1)] = s1;
                        }
                    }
                }
                if (c == 0 && zs == 4 && act0) {
                    *(float4*)&W[SWZ(gp * 4096 + 4 * u0)] =
                        make_float4(a[0][0], a[1][0], a[2][0], a[3][0]);
                    if (act1)
                        *(float4*)&W[SWZ(gp * 4096 + 4 * u0 + 4)] =
                            make_float4(a[0][1], a[1][1], a[2][1], a[3][1]);
                }
            }
        }
    }
    __syncthreads();
    // after (5,5): only g'=0, z=0, u=0 live -> the amplitude sits at W[0]
    if (t == 0) out[b] = W[0];
}

extern "C" void kernel_launch(void* const* d_in, const int* in_sizes, int n_in,
                              void* d_out, int out_size, void* d_ws, size_t ws_size,
                              hipStream_t stream) {
    const int*   X  = (const int*)d_in[0];     // x: [1024, 36] int32
    const float* Tg = (const float*)d_in[1];   // T: [6,6,2,4,4,4,4] fp32
    float* out = (float*)d_out;                // reference output: float32
    float* Tm  = (float*)d_ws;                 // 73,728 B scratch
    (void)in_sizes; (void)n_in; (void)ws_size; (void)out_size;
    peps_reorder_kernel<<<dim3(72), dim3(256), 0, stream>>>(Tg, Tm);
    peps_amp_kernel<<<dim3(BATCH), dim3(512), 0, stream>>>(X, Tm, out);
}

// Round 12
// 371.793 us; speedup vs baseline: 2.2484x; 2.2484x over previous
//
#include <hip/hip_runtime.h>

#define NROW 6
#define NCOL 6
#define BATCH 1024
#define NSITE 36

// LDS bank-conflict swizzle: XOR dword-addr bits [4:2] with bits [7:5].
// Preserves bits [1:0]; constant within any aligned 4-dword window, so
// float4/float2 accesses stay contiguous/aligned; SWZ(0)==0.
__device__ __forceinline__ int SWZ(int a) { return a ^ (((a >> 5) & 7) << 2); }

// Wave-uniform scalar-memory pointer: address_space(4) = AMDGPU constant.
// SCALAR float loads (no HIP_vector_type — its copy-ctor can't bind an AS(4)
// reference, which broke R11's compile). Adjacent scalar loads at literal
// offsets merge into s_load_dwordx4/x16: ONE SMEM fetch per wave instead of
// 64 lanes of global_load_dwordx4 — R9's binder.
typedef const float __attribute__((address_space(4))) * fcp;

// Pre-transpose T[site][spin][u=x][r=gp][d=z][l=g] into
// Tm[(site*2+spin)*256 + (gp*4+z)*16 + (g*4+x)]  (73,728 B in d_ws) so the
// main kernel's M rows are contiguous at wave-uniform addresses.
__global__ void peps_reorder_kernel(const float* __restrict__ T,
                                    float* __restrict__ Tm)
{
    int idx = blockIdx.x * 256 + threadIdx.x;   // [0, 18432)
    if (idx >= NSITE * 2 * 256) return;
    int i  = idx & 15;          // i = g*4 + x
    int o  = (idx >> 4) & 15;   // o = gp*4 + z
    int sp = (idx >> 8) & 1;
    int st = idx >> 9;
    int g = i >> 2, x = i & 3, gp = o >> 2, z = o & 3;
    Tm[idx] = T[st * 512 + sp * 256 + x * 64 + gp * 16 + z * 4 + g];
}

// Fixed-slot in-place contraction (R8/R9's verified algebra): state index =
// g*4096 + sum_j slot_j*4^j; step (row,c) reads up-bond x from slot c and
// writes down-bond z back into slot c. ONE barrier/step. State in LDS (64 KB,
// swizzled). Runtime row/c loops (R10's full unroll spilled 3.5 GB — never
// again). M loads via AS(4) scalar pointer -> s_load (see fcp above).
__global__ __launch_bounds__(512, 4)
void peps_amp_kernel(const int* __restrict__ X, const float* __restrict__ Tm,
                     float* __restrict__ out)
{
    __shared__ float W[16384];   // 65536 B exactly (4^7 fixed-slot state)

    const int b = blockIdx.x;
    const int t = threadIdx.x;
    const int* xrow = X + b * NSITE;

    // PHYS=2: pack the 36 spins into one scalar 64-bit mask (SGPR-resident
    // so every Tm address below is provably wave-uniform).
    unsigned long long sm = 0ull;
    const int4* xp = (const int4*)xrow;
    #pragma unroll
    for (int k = 0; k < 9; ++k) {
        int4 v = xp[k];
        sm |= ((unsigned long long)(v.x & 1)) << (4 * k + 0);
        sm |= ((unsigned long long)(v.y & 1)) << (4 * k + 1);
        sm |= ((unsigned long long)(v.z & 1)) << (4 * k + 2);
        sm |= ((unsigned long long)(v.w & 1)) << (4 * k + 3);
    }
    {
        unsigned lo = __builtin_amdgcn_readfirstlane((int)(sm & 0xffffffffull));
        unsigned hi = __builtin_amdgcn_readfirstlane((int)(sm >> 32));
        sm = ((unsigned long long)hi << 32) | lo;
    }

    if (t == 0) W[0] = 1.0f;     // seed (SWZ(0)==0); covered by step-0 barrier

    const int u0 = 2 * t;        // this thread's two spectators: u0, u0+1
    int step = 0;
    for (int row = 0; row < NROW; ++row) {
        const int xs = (row == 0) ? 1 : 4;          // up-bond size
        const int zs = (row == NROW - 1) ? 1 : 4;   // down-bond size
        for (int c = 0; c < NCOL; ++c, ++step) {
            const int gin  = (c == 0) ? 1 : 4;
            const int gout = (c == NCOL - 1) ? 1 : 4;
            const int lowb  = (zs == 4) ? 2 * c : 0;
            const int highb = (xs == 4) ? 2 * (5 - c) : 0;
            const int scount = 1 << (lowb + highb);
            const int p4c = 1 << (2 * c);
            const int lowmask = (1 << lowb) - 1;
            const int mr0 = ((u0 >> lowb) << (2 * c + 2)) | (u0 & lowmask);
            const int mr1 = (((u0 + 1) >> lowb) << (2 * c + 2)) | ((u0 + 1) & lowmask);
            const bool act0 = (u0 < scount);
            const bool act1 = (u0 + 1 < scount);

            // uniform scalar: spin bit + M base for this step (SMEM pointer)
            const int spin = (int)((sm >> step) & 1ull);
            const fcp Msf = (fcp)(unsigned long long)
                (const void*)(Tm + (size_t)(step * 2 + spin) * 256);

            __syncthreads();     // the ONLY barrier per step

            // ---- read phase (divergent, thread-private addresses) ----
            float in[16][2];
            if (act0) {
                if (c == 0) {
                    #pragma unroll
                    for (int g = 0; g < 4; ++g) if (g < gin) {
                        float4 r0 = *(const float4*)&W[SWZ(g * 4096 + 4 * u0)];
                        in[g*4+0][0]=r0.x; in[g*4+1][0]=r0.y;
                        in[g*4+2][0]=r0.z; in[g*4+3][0]=r0.w;
                        if (act1) {
                            float4 r1 = *(const float4*)&W[SWZ(g * 4096 + 4 * u0 + 4)];
                            in[g*4+0][1]=r1.x; in[g*4+1][1]=r1.y;
                            in[g*4+2][1]=r1.z; in[g*4+3][1]=r1.w;
                        } else {
                            in[g*4+0][1]=0.f; in[g*4+1][1]=0.f;
                            in[g*4+2][1]=0.f; in[g*4+3][1]=0.f;
                        }
                    }
                } else if (zs == 4) {
                    #pragma unroll
                    for (int g = 0; g < 4; ++g) if (g < gin) {
                        #pragma unroll
                        for (int x = 0; x < 4; ++x) if (x < xs) {
                            float2 r = *(const float2*)&W[SWZ(g * 4096 + x * p4c + mr0)];
                            in[g*4+x][0] = r.x; in[g*4+x][1] = r.y;
                        }
                    }
                } else {
                    #pragma unroll
                    for (int g = 0; g < 4; ++g) if (g < gin) {
                        #pragma unroll
                        for (int x = 0; x < 4; ++x) if (x < xs) {
                            in[g*4+x][0] = W[SWZ(g * 4096 + x * p4c + mr0)];
                            in[g*4+x][1] = act1 ? W[SWZ(g * 4096 + x * p4c + mr1)] : 0.f;
                        }
                    }
                }
            }

            // ---- compute + write; M via s_load (uniform, invariant) ----
            #pragma unroll
            for (int gp = 0; gp < 4; ++gp) if (gp < gout) {
                float a[4][2];
                #pragma unroll
                for (int z = 0; z < 4; ++z) if (z < zs) {
                    const int mb = (gp * 4 + z) * 16;
                    float mm[16];
                    #pragma unroll
                    for (int j = 0; j < 4; ++j) mm[j] = Msf[mb + j];
                    if (gin == 4) {
                        #pragma unroll
                        for (int j = 4; j < 16; ++j) mm[j] = Msf[mb + j];
                    }
                    float s0 = 0.f, s1 = 0.f;
                    if (act0) {
                        #pragma unroll
                        for (int g = 0; g < 4; ++g) if (g < gin) {
                            s0 += mm[g*4+0] * in[g*4+0][0];
                            s1 += mm[g*4+0] * in[g*4+0][1];
                            if (xs == 4) {
                                s0 += mm[g*4+1] * in[g*4+1][0];
                                s1 += mm[g*4+1] * in[g*4+1][1];
                                s0 += mm[g*4+2] * in[g*4+2][0];
                                s1 += mm[g*4+2] * in[g*4+2][1];
                                s0 += mm[g*4+3] * in[g*4+3][0];
                                s1 += mm[g*4+3] * in[g*4+3][1];
                            }
                        }
                    }
                    a[z][0] = s0; a[z][1] = s1;
                    if (act0) {
                        if (c != 0 && zs == 4) {
                            *(float2*)&W[SWZ(gp * 4096 + z * p4c + mr0)] =
                                make_float2(s0, s1);
                        } else if (zs == 1) {
                            W[SWZ(gp * 4096 + mr0)] = s0;
                            if (act1) W[SWZ(gp * 4096 + mr1)] = s1;
                        }
                    }
                }
                if (c == 0 && zs == 4 && act0) {
                    *(float4*)&W[SWZ(gp * 4096 + 4 * u0)] =
                        make_float4(a[0][0], a[1][0], a[2][0], a[3][0]);
                    if (act1)
                        *(float4*)&W[SWZ(gp * 4096 + 4 * u0 + 4)] =
                            make_float4(a[0][1], a[1][1], a[2][1], a[3][1]);
                }
            }
        }
    }
    __syncthreads();
    // after (5,5): only g'=0, z=0, u=0 live -> the amplitude sits at W[0]
    if (t == 0) out[b] = W[0];
}

extern "C" void kernel_launch(void* const* d_in, const int* in_sizes, int n_in,
                              void* d_out, int out_size, void* d_ws, size_t ws_size,
                              hipStream_t stream) {
    const int*   X  = (const int*)d_in[0];     // x: [1024, 36] int32
    const float* Tg = (const float*)d_in[1];   // T: [6,6,2,4,4,4,4] fp32
    float* out = (float*)d_out;                // reference output: float32
    float* Tm  = (float*)d_ws;                 // 73,728 B scratch
    (void)in_sizes; (void)n_in; (void)ws_size; (void)out_size;
    peps_reorder_kernel<<<dim3(72), dim3(256), 0, stream>>>(Tg, Tm);
    peps_amp_kernel<<<dim3(BATCH), dim3(512), 0, stream>>>(X, Tm, out);
}